// Round 1
// baseline (487.944 us; speedup 1.0000x reference)
//
#include <hip/hip_runtime.h>

// CRF log-likelihood, MI355X. SEQ=512, B=1024, T=48.
// One wave per batch chain, one lane per tag. E=exp(trans) columns in VGPRs,
// matvec via readlane-broadcast + fmac. Numerator fused. ws holds per-batch llh.

constexpr int SEQ = 512, BN = 1024, TT = 48;
#define LOG2E 1.44269504088896340736f
#define LN2   0.69314718055994530942f

__global__ __launch_bounds__(256) void crf_fwd(
    const float* __restrict__ emis, const int* __restrict__ tags,
    const int* __restrict__ mask, const float* __restrict__ start_t,
    const float* __restrict__ end_t, const float* __restrict__ trans,
    float* __restrict__ ws)
{
    __shared__ float ltr[TT * TT];
    const int tid = threadIdx.x;
    for (int i = tid; i < TT * TT; i += 256) ltr[i] = trans[i];
    __syncthreads();

    const int lane = tid & 63;
    const int wave = tid >> 6;
    const int b = __builtin_amdgcn_readfirstlane(blockIdx.x * 4 + wave);
    const bool jv = (lane < TT);
    const int jc = jv ? lane : (TT - 1);

    // lane j holds column j of E = exp(transitions): E[i][j], i=0..47
    float Ecol[TT];
#pragma unroll
    for (int i = 0; i < TT; ++i)
        Ecol[i] = exp2f(ltr[i * TT + jc] * LOG2E);

    const float st = start_t[jc];
    const float en = end_t[jc];

    // t = 0
    float e0 = jv ? emis[(size_t)b * TT + lane] : 0.f;
    float s  = jv ? (st + e0) : -1e30f;
    int tag_prev = tags[b];
    float numpart = (lane == tag_prev) ? (st + e0) : 0.f;

    float e_cur = jv ? emis[((size_t)BN + b) * TT + lane] : 0.f;  // t=1 row

    for (int t = 1; t < SEQ; ++t) {
        // prefetch next emission row (independent of the serial chain)
        float e_next = 0.f;
        if (t + 1 < SEQ && jv)
            e_next = emis[((size_t)(t + 1) * BN + b) * TT + lane];
        const int tag_t = tags[t * BN + b];
        const int m_t   = mask[t * BN + b];

        // wave max over the 48 valid lanes (pad lanes carry -1e30)
        float m = s;
#pragma unroll
        for (int d = 1; d < 64; d <<= 1)
            m = fmaxf(m, __shfl_xor(m, d, 64));

        const float p = exp2f((s - m) * LOG2E);   // 0 for pad lanes

        // q_j = sum_i p_i * E[i][j]; p_i broadcast via readlane (const idx)
        float q0 = 0.f, q1 = 0.f, q2 = 0.f, q3 = 0.f;
#pragma unroll
        for (int i = 0; i < TT; i += 4) {
            const float p0 = __int_as_float(__builtin_amdgcn_readlane(__float_as_int(p), i));
            const float p1 = __int_as_float(__builtin_amdgcn_readlane(__float_as_int(p), i + 1));
            const float p2 = __int_as_float(__builtin_amdgcn_readlane(__float_as_int(p), i + 2));
            const float p3 = __int_as_float(__builtin_amdgcn_readlane(__float_as_int(p), i + 3));
            q0 = fmaf(p0, Ecol[i],     q0);
            q1 = fmaf(p1, Ecol[i + 1], q1);
            q2 = fmaf(p2, Ecol[i + 2], q2);
            q3 = fmaf(p3, Ecol[i + 3], q3);
        }
        const float q = (q0 + q1) + (q2 + q3);
        const float snew = m + log2f(q) * LN2 + e_cur;

        if (m_t) {  // wave-uniform (scalar load)
            s = jv ? snew : -1e30f;
            numpart += (lane == tag_t) ? e_cur : 0.f;
            numpart += (lane == 0) ? ltr[tag_prev * TT + tag_t] : 0.f;
            tag_prev = tag_t;
        }
        e_cur = e_next;
    }

    // numerator: end transition of last (masked) tag
    numpart += (lane == tag_prev) ? en : 0.f;

    // denominator: logsumexp(s + end)
    float v = jv ? (s + en) : -1e30f;
    float m2 = v;
#pragma unroll
    for (int d = 1; d < 64; d <<= 1)
        m2 = fmaxf(m2, __shfl_xor(m2, d, 64));
    float se = exp2f((v - m2) * LOG2E);
#pragma unroll
    for (int d = 1; d < 64; d <<= 1)
        se += __shfl_xor(se, d, 64);
    const float den = m2 + log2f(se) * LN2;

    float num = numpart;
#pragma unroll
    for (int d = 1; d < 64; d <<= 1)
        num += __shfl_xor(num, d, 64);

    if (lane == 0) ws[b] = num - den;
}

__global__ __launch_bounds__(256) void reduce_mean(
    const float* __restrict__ ws, float* __restrict__ out)
{
    const int tid = threadIdx.x;
    float v = ws[tid] + ws[tid + 256] + ws[tid + 512] + ws[tid + 768];
#pragma unroll
    for (int d = 1; d < 64; d <<= 1)
        v += __shfl_xor(v, d, 64);
    __shared__ float acc[4];
    if ((tid & 63) == 0) acc[tid >> 6] = v;
    __syncthreads();
    if (tid == 0) out[0] = (acc[0] + acc[1] + acc[2] + acc[3]) * (1.f / 1024.f);
}

extern "C" void kernel_launch(void* const* d_in, const int* in_sizes, int n_in,
                              void* d_out, int out_size, void* d_ws, size_t ws_size,
                              hipStream_t stream)
{
    const float* emis    = (const float*)d_in[0];
    const int*   tags    = (const int*)d_in[1];
    const int*   mask    = (const int*)d_in[2];
    const float* start_t = (const float*)d_in[3];
    const float* end_t   = (const float*)d_in[4];
    const float* trans   = (const float*)d_in[5];
    float* ws  = (float*)d_ws;
    float* out = (float*)d_out;

    crf_fwd<<<dim3(BN / 4), dim3(256), 0, stream>>>(emis, tags, mask, start_t, end_t, trans, ws);
    reduce_mean<<<dim3(1), dim3(256), 0, stream>>>(ws, out);
}

// Round 2
// 287.755 us; speedup vs baseline: 1.6957x; 1.6957x over previous
//
#include <hip/hip_runtime.h>

// CRF log-likelihood, MI355X. SEQ=512, B=1024, T=48.
// One wave (64-thread block) per batch chain, lane = tag.
// E=exp(trans) columns in 24 f32x2 regs; p broadcast via LDS float4 reads;
// tags/mask chunk-preloaded via lanes; emissions 8-deep register pipeline.

constexpr int SEQ = 512, BN = 1024, TT = 48;
#define LOG2E 1.44269504088896340736f
#define LN2   0.69314718055994530942f

typedef float f32x2 __attribute__((ext_vector_type(2)));
typedef float f32x4 __attribute__((ext_vector_type(4)));

__global__ __launch_bounds__(64, 1) void crf_fwd(
    const float* __restrict__ emis, const int* __restrict__ tags,
    const int* __restrict__ mask, const float* __restrict__ start_t,
    const float* __restrict__ end_t, const float* __restrict__ trans,
    float* __restrict__ ws)
{
    __shared__ float ltr[TT * TT];
    __shared__ __align__(16) float pbuf[2][64];

    const int lane = threadIdx.x;
    const int b = blockIdx.x;

    for (int i = lane; i < TT * TT; i += 64) ltr[i] = trans[i];
    __syncthreads();

    const bool jv = (lane < TT);
    const int jc = jv ? lane : (TT - 1);

    // lane j holds column j of E = exp(transitions), packed as 24 f32x2
    f32x2 E[24];
#pragma unroll
    for (int k = 0; k < 24; ++k) {
        E[k].x = exp2f(ltr[(2 * k) * TT + jc] * LOG2E);
        E[k].y = exp2f(ltr[(2 * k + 1) * TT + jc] * LOG2E);
    }

    const float st = start_t[jc];
    const float en = end_t[jc];

    // emission pipeline: ep[t&7] holds row t, loaded 8 steps ahead
    const float* eb = emis + (size_t)b * TT + jc;
    float ep[8];
#pragma unroll
    for (int k = 0; k < 8; ++k) ep[k] = eb[(size_t)k * BN * TT];

    const int tag0 = __builtin_amdgcn_readfirstlane(tags[b]);
    float s = jv ? (st + ep[0]) : -1e30f;
    float numpart = (lane == tag0) ? (st + ep[0]) : 0.f;
    float numtr = 0.f;            // uniform across lanes
    int tag_prev = tag0;          // uniform

    // first chunk's tags/mask (lane l covers step l)
    int tgv = tags[(size_t)lane * BN + b];
    int mkv = mask[(size_t)lane * BN + b];

    for (int c = 0; c < 8; ++c) {
        const int tbase = c * 64;
        // encode mask into tag; step 0 force-disabled (handled in init)
        const int tmv = (mkv && (tbase + lane) > 0) ? tgv : -1;
        // prefetch next chunk's tags/mask (used 64 steps later)
        int tgn = 0, mkn = 0;
        if (c < 7) {
            tgn = tags[((size_t)(tbase + 64) + lane) * BN + b];
            mkn = mask[((size_t)(tbase + 64) + lane) * BN + b];
        }

#pragma unroll 8
        for (int u = 0; u < 64; ++u) {
            const int t = tbase + u;
            const int tmu = __builtin_amdgcn_readlane(tmv, u);  // uniform
            const float e_cur = ep[u & 7];
            if (t + 8 < SEQ)
                ep[u & 7] = eb[(size_t)(t + 8) * BN * TT];

            const float s0 = __builtin_amdgcn_readfirstlane(s);
            const float p = exp2f((s - s0) * LOG2E);  // 0 for pad lanes
            pbuf[t & 1][lane] = p;
            __syncthreads();  // 1-wave block: lowers to lgkmcnt wait

            const f32x4* pb = (const f32x4*)pbuf[t & 1];
            f32x2 a0 = {0.f, 0.f}, a1 = {0.f, 0.f};
            f32x2 a2 = {0.f, 0.f}, a3 = {0.f, 0.f};
#pragma unroll
            for (int k = 0; k < 12; ++k) {
                const f32x4 v = pb[k];
                const f32x2 lo = {v.x, v.y}, hi = {v.z, v.w};
                if (k & 1) {
                    a2 = __builtin_elementwise_fma(lo, E[2 * k],     a2);
                    a3 = __builtin_elementwise_fma(hi, E[2 * k + 1], a3);
                } else {
                    a0 = __builtin_elementwise_fma(lo, E[2 * k],     a0);
                    a1 = __builtin_elementwise_fma(hi, E[2 * k + 1], a1);
                }
            }
            const f32x2 qa = (a0 + a1) + (a2 + a3);
            const float q = qa.x + qa.y;
            const float snew = fmaf(log2f(q), LN2, s0) + e_cur;

            if (tmu >= 0) {  // uniform branch (mask & step-validity)
                s = jv ? snew : -1e30f;
                numpart += (lane == tmu) ? e_cur : 0.f;
                numtr += ltr[tag_prev * TT + tmu];  // broadcast ds_read
                tag_prev = tmu;
            }
        }
        tgv = tgn;
        mkv = mkn;
    }

    // numerator: end transition at last masked tag
    numpart += (lane == tag_prev) ? en : 0.f;

    // denominator: exact logsumexp(s + end) over 48 lanes
    float v = jv ? (s + en) : -1e30f;
    float m2 = v;
#pragma unroll
    for (int d = 1; d < 64; d <<= 1)
        m2 = fmaxf(m2, __shfl_xor(m2, d, 64));
    float se = exp2f((v - m2) * LOG2E);
#pragma unroll
    for (int d = 1; d < 64; d <<= 1)
        se += __shfl_xor(se, d, 64);
    const float den = m2 + log2f(se) * LN2;

    float num = numpart;
#pragma unroll
    for (int d = 1; d < 64; d <<= 1)
        num += __shfl_xor(num, d, 64);
    num += numtr;  // uniform value, add once after reduce

    if (lane == 0) ws[b] = num - den;
}

__global__ __launch_bounds__(256) void reduce_mean(
    const float* __restrict__ ws, float* __restrict__ out)
{
    const int tid = threadIdx.x;
    float v = ws[tid] + ws[tid + 256] + ws[tid + 512] + ws[tid + 768];
#pragma unroll
    for (int d = 1; d < 64; d <<= 1)
        v += __shfl_xor(v, d, 64);
    __shared__ float acc[4];
    if ((tid & 63) == 0) acc[tid >> 6] = v;
    __syncthreads();
    if (tid == 0) out[0] = (acc[0] + acc[1] + acc[2] + acc[3]) * (1.f / 1024.f);
}

extern "C" void kernel_launch(void* const* d_in, const int* in_sizes, int n_in,
                              void* d_out, int out_size, void* d_ws, size_t ws_size,
                              hipStream_t stream)
{
    const float* emis    = (const float*)d_in[0];
    const int*   tags    = (const int*)d_in[1];
    const int*   mask    = (const int*)d_in[2];
    const float* start_t = (const float*)d_in[3];
    const float* end_t   = (const float*)d_in[4];
    const float* trans   = (const float*)d_in[5];
    float* ws  = (float*)d_ws;
    float* out = (float*)d_out;

    crf_fwd<<<dim3(BN), dim3(64), 0, stream>>>(emis, tags, mask, start_t, end_t, trans, ws);
    reduce_mean<<<dim3(1), dim3(256), 0, stream>>>(ws, out);
}

// Round 3
// 266.333 us; speedup vs baseline: 1.8321x; 1.0804x over previous
//
#include <hip/hip_runtime.h>

// CRF log-likelihood, MI355X. SEQ=512, B=1024, T=48.
// One wave (64-thread block) per batch chain, lane = tag.
// No barriers/LDS on the serial chain: p broadcast via v_readlane + fmac.
// E=exp(trans) columns in 48 VGPRs; emissions 8-deep register pipeline;
// tags/mask chunk-preloaded; trans-numerator gathered chunk-parallel.

constexpr int SEQ = 512, BN = 1024, TT = 48;
#define LOG2E 1.44269504088896340736f
#define LN2   0.69314718055994530942f

__device__ __forceinline__ float fexp2(float x) { return __builtin_amdgcn_exp2f(x); }
__device__ __forceinline__ float flog2(float x) { return __builtin_amdgcn_logf(x); }
__device__ __forceinline__ float rlane(float v, int i) {
    return __int_as_float(__builtin_amdgcn_readlane(__float_as_int(v), i));
}

__global__ __launch_bounds__(64, 1) void crf_fwd(
    const float* __restrict__ emis, const int* __restrict__ tags,
    const int* __restrict__ mask, const float* __restrict__ start_t,
    const float* __restrict__ end_t, const float* __restrict__ trans,
    float* __restrict__ ws)
{
    __shared__ float ltr[TT * TT];
    const int lane = threadIdx.x;
    const int b = blockIdx.x;

    for (int i = lane; i < TT * TT; i += 64) ltr[i] = trans[i];
    __syncthreads();  // once, outside the serial loop

    const bool jv = (lane < TT);
    const int jc = jv ? lane : (TT - 1);

    // lane j holds column j of E = exp(transitions): E[i] = exp(trans[i][j])
    float E[TT];
#pragma unroll
    for (int i = 0; i < TT; ++i)
        E[i] = fexp2(ltr[i * TT + jc] * LOG2E);

    const float st = start_t[jc];
    const float en = end_t[jc];

    // emission pipeline: ep[t&7] holds row t, loaded 8 steps ahead
    const float* eb = emis + (size_t)b * TT + jc;
    float ep[8];
#pragma unroll
    for (int k = 0; k < 8; ++k) ep[k] = eb[(size_t)k * BN * TT];

    const int tag0 = tags[b];  // uniform
    float s = jv ? (st + ep[0]) : -1e30f;
    float numpart = (lane == tag0) ? (st + ep[0]) : 0.f;
    float numtr = 0.f;   // per-lane trans-numerator accumulator
    int mcount = 0;      // sum of mask over all steps (uniform)
    int carry_tag = tag0;

    // first chunk's tags/mask (lane u covers step u)
    int tgv = tags[(size_t)lane * BN + b];
    int mkv = mask[(size_t)lane * BN + b];

    for (int c = 0; c < 8; ++c) {
        const int tbase = c * 64;
        // valid = masked and not step 0; encode as tag-or-minus-one
        const int tmv = (mkv && (tbase + lane) > 0) ? tgv : -1;

        // chunk-parallel numerator: trans[tag[t-1], tag[t]] * mask[t]
        int tprev = __shfl_up(tgv, 1, 64);
        if (lane == 0) tprev = carry_tag;
        if (tmv >= 0) numtr += ltr[tprev * TT + tgv];
        carry_tag = __builtin_amdgcn_readlane(tgv, 63);
        mcount += __popcll(__ballot(mkv != 0));

        // prefetch next chunk's tags/mask
        int tgn = 0, mkn = 0;
        if (c < 7) {
            tgn = tags[((size_t)(tbase + 64) + lane) * BN + b];
            mkn = mask[((size_t)(tbase + 64) + lane) * BN + b];
        }

#pragma unroll 8
        for (int u = 0; u < 64; ++u) {
            const int t = tbase + u;
            const int tmu = __builtin_amdgcn_readlane(tmv, u);  // uniform
            const float e_cur = ep[u & 7];
            if (t + 8 < SEQ)
                ep[u & 7] = eb[(size_t)(t + 8) * BN * TT];

            const float s0 = __builtin_amdgcn_readfirstlane(s);
            const float p = fexp2((s - s0) * LOG2E);  // 0 for pad lanes

            // q_j = sum_i p_i * E[i][j]; p_i broadcast via readlane (const idx)
            float q0 = 0.f, q1 = 0.f, q2 = 0.f, q3 = 0.f;
#pragma unroll
            for (int i = 0; i < TT; i += 4) {
                q0 = fmaf(rlane(p, i),     E[i],     q0);
                q1 = fmaf(rlane(p, i + 1), E[i + 1], q1);
                q2 = fmaf(rlane(p, i + 2), E[i + 2], q2);
                q3 = fmaf(rlane(p, i + 3), E[i + 3], q3);
            }
            const float q = (q0 + q1) + (q2 + q3);
            const float snew = fmaf(flog2(q), LN2, s0) + e_cur;

            if (tmu >= 0) {  // uniform branch (mask & step-validity)
                s = jv ? snew : -1e30f;
                numpart += (lane == tmu) ? e_cur : 0.f;
            }
        }
        tgv = tgn;
        mkv = mkn;
    }

    // numerator: end transition at tags[sum(mask)-1]
    const int last_tag = tags[(size_t)(mcount - 1) * BN + b];  // uniform
    numpart += (lane == last_tag) ? en : 0.f;
    numpart += numtr;

    // denominator: exact logsumexp(s + end) over 48 lanes
    float v = jv ? (s + en) : -1e30f;
    float m2 = v;
#pragma unroll
    for (int d = 1; d < 64; d <<= 1)
        m2 = fmaxf(m2, __shfl_xor(m2, d, 64));
    float se = fexp2((v - m2) * LOG2E);
#pragma unroll
    for (int d = 1; d < 64; d <<= 1)
        se += __shfl_xor(se, d, 64);
    const float den = fmaf(flog2(se), LN2, m2);

    float num = numpart;
#pragma unroll
    for (int d = 1; d < 64; d <<= 1)
        num += __shfl_xor(num, d, 64);

    if (lane == 0) ws[b] = num - den;
}

__global__ __launch_bounds__(256) void reduce_mean(
    const float* __restrict__ ws, float* __restrict__ out)
{
    const int tid = threadIdx.x;
    float v = ws[tid] + ws[tid + 256] + ws[tid + 512] + ws[tid + 768];
#pragma unroll
    for (int d = 1; d < 64; d <<= 1)
        v += __shfl_xor(v, d, 64);
    __shared__ float acc[4];
    if ((tid & 63) == 0) acc[tid >> 6] = v;
    __syncthreads();
    if (tid == 0) out[0] = (acc[0] + acc[1] + acc[2] + acc[3]) * (1.f / 1024.f);
}

extern "C" void kernel_launch(void* const* d_in, const int* in_sizes, int n_in,
                              void* d_out, int out_size, void* d_ws, size_t ws_size,
                              hipStream_t stream)
{
    const float* emis    = (const float*)d_in[0];
    const int*   tags    = (const int*)d_in[1];
    const int*   mask    = (const int*)d_in[2];
    const float* start_t = (const float*)d_in[3];
    const float* end_t   = (const float*)d_in[4];
    const float* trans   = (const float*)d_in[5];
    float* ws  = (float*)d_ws;
    float* out = (float*)d_out;

    crf_fwd<<<dim3(BN), dim3(64), 0, stream>>>(emis, tags, mask, start_t, end_t, trans, ws);
    reduce_mean<<<dim3(1), dim3(256), 0, stream>>>(ws, out);
}

// Round 4
// 112.615 us; speedup vs baseline: 4.3328x; 2.3650x over previous
//
#include <hip/hip_runtime.h>

// CRF log-likelihood, MI355X. SEQ=512, B=1024, T=48.
// One wave (64-thread block) per batch chain, lane = tag.
// E=exp(trans) pinned in 48 VGPRs (asm keep-alive). Emissions staged per
// 64-step chunk into double-buffered LDS via global_load_lds (one vmcnt wait
// per chunk); per-step e via 4-deep ds_read pipeline. Matvec via readlane
// broadcast + fmac. Numerator computed chunk-parallel, off the serial chain.

constexpr int SEQ = 512, BN = 1024, TT = 48;
constexpr int CH = 64, NCH = SEQ / CH;
#define LOG2E 1.44269504088896340736f
#define LN2   0.69314718055994530942f

__device__ __forceinline__ float fexp2(float x) { return __builtin_amdgcn_exp2f(x); }
__device__ __forceinline__ float flog2(float x) { return __builtin_amdgcn_logf(x); }
__device__ __forceinline__ float rlane(float v, int i) {
    return __int_as_float(__builtin_amdgcn_readlane(__float_as_int(v), i));
}

__global__ __launch_bounds__(64, 1) void crf_fwd(
    const float* __restrict__ emis, const int* __restrict__ tags,
    const int* __restrict__ mask, const float* __restrict__ start_t,
    const float* __restrict__ end_t, const float* __restrict__ trans,
    float* __restrict__ ws)
{
    __shared__ float ltr[TT * TT];
    __shared__ __align__(16) float ebuf[2][CH * TT];  // 2 x 12 KB

    const int lane = threadIdx.x;
    const int b = blockIdx.x;

    for (int i = lane; i < TT * TT; i += 64) ltr[i] = trans[i];
    __syncthreads();  // once, outside the serial loop

    const bool jv = (lane < TT);
    const int jc = jv ? lane : (TT - 1);

    // lane j holds column j of E = exp(transitions); pin into VGPRs
    float E[TT];
#pragma unroll
    for (int i = 0; i < TT; ++i)
        E[i] = fexp2(ltr[i * TT + jc] * LOG2E);
#pragma unroll
    for (int i = 0; i < TT; ++i)
        asm volatile("" : "+v"(E[i]));

    const float st = start_t[jc];
    const float en = end_t[jc];

    // per-lane byte offsets (within a chunk block) for the 12 staging instrs:
    // float4 g = k*64+lane covers (row r = g/12, quad j4 = g%12)
    int offs[12];
#pragma unroll
    for (int k = 0; k < 12; ++k) {
        const int g = k * 64 + lane;
        const int r = g / 12, j4 = g % 12;
        offs[k] = r * (BN * TT * 4) + j4 * 16;
    }

#define STAGE_CHUNK(tb, buf)                                                   \
    {                                                                          \
        const char* cb = (const char*)emis + ((size_t)(tb) * BN + b) * (TT * 4); \
        _Pragma("unroll")                                                      \
        for (int k = 0; k < 12; ++k) {                                         \
            __builtin_amdgcn_global_load_lds(                                  \
                (const __attribute__((address_space(1))) void*)(cb + offs[k]), \
                (__attribute__((address_space(3))) void*)(&ebuf[buf][k * 256]),\
                16, 0, 0);                                                     \
        }                                                                      \
    }

    // prologue: stage chunk 0, first tags/mask chunk
    STAGE_CHUNK(0, 0);
    int tgv = tags[(size_t)lane * BN + b];
    int mkv = mask[(size_t)lane * BN + b];
    const int tag0 = tags[b];
    asm volatile("s_waitcnt vmcnt(0)" ::: "memory");
    __builtin_amdgcn_sched_barrier(0);

    float epipe[4];
#pragma unroll
    for (int k = 0; k < 4; ++k) epipe[k] = ebuf[0][k * TT + jc];

    float s = jv ? (st + epipe[0]) : -1e30f;
    float numpart = (lane == tag0) ? (st + epipe[0]) : 0.f;
    float numtr = 0.f, numem = 0.f;  // per-lane chunk-parallel accumulators
    int mcount = 0;                  // uniform: sum of mask
    int carry_tag = tag0;
    int cur = 0;

    for (int c = 0; c < NCH; ++c) {
        const int tbase = c * CH;
        const float* ebc = ebuf[cur];

        // ---- chunk-parallel numerator (off the serial chain) ----
        const int tmv = (mkv && (tbase + lane) > 0) ? tgv : -1;
        int tprev = __shfl_up(tgv, 1, 64);
        if (lane == 0) tprev = carry_tag;
        if (tmv >= 0) {
            numtr += ltr[tprev * TT + tgv];
            numem += ebc[lane * TT + tgv];
        }
        carry_tag = __builtin_amdgcn_readlane(tgv, 63);
        mcount += __popcll(__ballot(mkv != 0));

        // ---- stage next chunk (loads stay in flight across the whole chunk)
        int tgn = 0, mkn = 0;
        if (c < NCH - 1) {
            STAGE_CHUNK(tbase + CH, cur ^ 1);
            tgn = tags[((size_t)(tbase + CH) + lane) * BN + b];
            mkn = mask[((size_t)(tbase + CH) + lane) * BN + b];
        }

        // ---- 64 serial steps, no VMEM waits inside ----
#pragma unroll 4
        for (int u = 0; u < CH; ++u) {
            const int tmu = __builtin_amdgcn_readlane(tmv, u);  // uniform
            const float e_cur = epipe[u & 3];
            const int un = (u + 4 < CH) ? (u + 4) : (CH - 1);   // clamped refill
            epipe[u & 3] = ebc[un * TT + jc];

            const float s0 = __builtin_amdgcn_readfirstlane(s);
            const float p = fexp2((s - s0) * LOG2E);  // 0 for pad lanes

            float q0 = 0.f, q1 = 0.f, q2 = 0.f, q3 = 0.f;
#pragma unroll
            for (int i = 0; i < TT; i += 4) {
                q0 = fmaf(rlane(p, i),     E[i],     q0);
                q1 = fmaf(rlane(p, i + 1), E[i + 1], q1);
                q2 = fmaf(rlane(p, i + 2), E[i + 2], q2);
                q3 = fmaf(rlane(p, i + 3), E[i + 3], q3);
            }
            const float q = (q0 + q1) + (q2 + q3);
            const float snew = fmaf(flog2(q), LN2, s0) + e_cur;

            if (tmu >= 0)  // uniform branch
                s = jv ? snew : -1e30f;
        }

        // ---- chunk boundary: the ONLY vmcnt drain, amortized over 64 steps
        asm volatile("s_waitcnt vmcnt(0)" ::: "memory");
        __builtin_amdgcn_sched_barrier(0);
        cur ^= 1;
        tgv = tgn; mkv = mkn;
        if (c < NCH - 1) {
            const float* nb = ebuf[cur];
#pragma unroll
            for (int k = 0; k < 4; ++k) epipe[k] = nb[k * TT + jc];
        }
    }

    // numerator: end transition at tags[sum(mask)-1]
    const int last_tag = tags[(size_t)(mcount - 1) * BN + b];  // uniform
    numpart += (lane == last_tag) ? en : 0.f;
    numpart += numtr + numem;

    // denominator: exact logsumexp(s + end) over 48 lanes
    float v = jv ? (s + en) : -1e30f;
    float m2 = v;
#pragma unroll
    for (int d = 1; d < 64; d <<= 1)
        m2 = fmaxf(m2, __shfl_xor(m2, d, 64));
    float se = fexp2((v - m2) * LOG2E);
#pragma unroll
    for (int d = 1; d < 64; d <<= 1)
        se += __shfl_xor(se, d, 64);
    const float den = fmaf(flog2(se), LN2, m2);

    float num = numpart;
#pragma unroll
    for (int d = 1; d < 64; d <<= 1)
        num += __shfl_xor(num, d, 64);

    if (lane == 0) ws[b] = num - den;
#undef STAGE_CHUNK
}

__global__ __launch_bounds__(256) void reduce_mean(
    const float* __restrict__ ws, float* __restrict__ out)
{
    const int tid = threadIdx.x;
    float v = ws[tid] + ws[tid + 256] + ws[tid + 512] + ws[tid + 768];
#pragma unroll
    for (int d = 1; d < 64; d <<= 1)
        v += __shfl_xor(v, d, 64);
    __shared__ float acc[4];
    if ((tid & 63) == 0) acc[tid >> 6] = v;
    __syncthreads();
    if (tid == 0) out[0] = (acc[0] + acc[1] + acc[2] + acc[3]) * (1.f / 1024.f);
}

extern "C" void kernel_launch(void* const* d_in, const int* in_sizes, int n_in,
                              void* d_out, int out_size, void* d_ws, size_t ws_size,
                              hipStream_t stream)
{
    const float* emis    = (const float*)d_in[0];
    const int*   tags    = (const int*)d_in[1];
    const int*   mask    = (const int*)d_in[2];
    const float* start_t = (const float*)d_in[3];
    const float* end_t   = (const float*)d_in[4];
    const float* trans   = (const float*)d_in[5];
    float* ws  = (float*)d_ws;
    float* out = (float*)d_out;

    crf_fwd<<<dim3(BN), dim3(64), 0, stream>>>(emis, tags, mask, start_t, end_t, trans, ws);
    reduce_mean<<<dim3(1), dim3(256), 0, stream>>>(ws, out);
}